// Round 1
// baseline (1899.248 us; speedup 1.0000x reference)
//
#include <hip/hip_runtime.h>
#include <hip/hip_bf16.h>
#include <cstdint>

// Problem dims
// L=6, E=1024, H=16, F=4096, V=32000, B=4, S=512, ML=512, DH=64, tokens=2048

typedef float f32x4 __attribute__((ext_vector_type(4)));
typedef short s16x8 __attribute__((ext_vector_type(8)));
typedef __bf16 b16x8 __attribute__((ext_vector_type(8)));

// MFMA operand wrapper: converts to whichever vector type the builtin wants
// (older toolchains: short8; upstream gfx950 builtins: bf16x8).
struct Frag8 {
    s16x8 v;
    __device__ operator s16x8() const { return v; }
    __device__ operator b16x8() const { return __builtin_bit_cast(b16x8, v); }
};

__device__ __forceinline__ f32x4 mfma16(Frag8 a, Frag8 b, f32x4 c) {
    return __builtin_amdgcn_mfma_f32_16x16x32_bf16(a, b, c, 0, 0, 0);
}

__device__ __forceinline__ void gload_lds16(const void* g, void* l) {
    __builtin_amdgcn_global_load_lds(
        (__attribute__((address_space(1))) void*)g,
        (__attribute__((address_space(3))) void*)l, 16, 0, 0);
}

__device__ __forceinline__ unsigned short bf16bits(float x) {
    return __builtin_bit_cast(unsigned short, __float2bfloat16(x));
}

// ---------------- fp32 -> bf16 conversion ----------------
__global__ __launch_bounds__(256) void k_f32_to_bf16(const float* __restrict__ in,
                                                     __hip_bfloat16* __restrict__ out,
                                                     long n) {
    const long i = ((long)blockIdx.x * 256 + threadIdx.x) * 4;
    if (i >= n) return;
    const float4 v = *(const float4*)(in + i);
    ushort4 u;
    u.x = bf16bits(v.x); u.y = bf16bits(v.y); u.z = bf16bits(v.z); u.w = bf16bits(v.w);
    *(ushort4*)((unsigned short*)out + i) = u;
}

// ---------------- embedding gather ----------------
__global__ __launch_bounds__(256) void k_embed(const int* __restrict__ seq,
                                               const float* __restrict__ tok,
                                               float* __restrict__ x,
                                               __hip_bfloat16* __restrict__ xb) {
    const int t = blockIdx.x;             // token 0..2047
    const int tokid = seq[t];
    const float4 v = *(const float4*)(tok + (size_t)tokid * 1024 + threadIdx.x * 4);
    float4 o;
    o.x = v.x * 32.0f; o.y = v.y * 32.0f; o.z = v.z * 32.0f; o.w = v.w * 32.0f;  // sqrt(1024)=32
    *(float4*)(x + (size_t)t * 1024 + threadIdx.x * 4) = o;
    ushort4 u;
    u.x = bf16bits(o.x); u.y = bf16bits(o.y); u.z = bf16bits(o.z); u.w = bf16bits(o.w);
    *(ushort4*)((unsigned short*)xb + (size_t)t * 1024 + threadIdx.x * 4) = u;
}

// ---------------- GEMM: C[M,N] = A[M,K] * B[N,K]^T + bias, optional GELU ----------------
// 128x128 tile, BK=32, 4 waves each computing a 64x64 quadrant as 4x4 MFMA frags.
__global__ __launch_bounds__(256) void k_gemm_bt(const __hip_bfloat16* __restrict__ A,
                                                 const __hip_bfloat16* __restrict__ B,
                                                 const float* __restrict__ bias,
                                                 float* __restrict__ Cf,
                                                 __hip_bfloat16* __restrict__ Cb,
                                                 const int M, const int N, const int K,
                                                 const int act) {
    __shared__ __align__(16) __hip_bfloat16 As[128 * 32];
    __shared__ __align__(16) __hip_bfloat16 Bs[128 * 32];

    const int tid = threadIdx.x;
    const int lane = tid & 63, w = tid >> 6;
    const int wr = w >> 1, wc = w & 1;
    const int l16 = lane & 15, lq = lane >> 4;
    const int m0 = blockIdx.y * 128, n0 = blockIdx.x * 128;

    f32x4 acc[4][4] = {};

    for (int k0 = 0; k0 < K; k0 += 32) {
        __syncthreads();
#pragma unroll
        for (int i = 0; i < 2; ++i) {
            const int c = i * 256 + tid;          // 0..511 16B-chunks
            const int row = c >> 2, sl = c & 3;   // [row][sl*8 .. sl*8+7]
            gload_lds16(A + (size_t)(m0 + row) * K + k0 + sl * 8, (char*)As + c * 16);
            gload_lds16(B + (size_t)(n0 + row) * K + k0 + sl * 8, (char*)Bs + c * 16);
        }
        __syncthreads();

        Frag8 af[4], bfr[4];
#pragma unroll
        for (int mi = 0; mi < 4; ++mi)
            af[mi].v = *(const s16x8*)((const char*)As + (wr * 64 + mi * 16 + l16) * 64 + lq * 16);
#pragma unroll
        for (int ni = 0; ni < 4; ++ni)
            bfr[ni].v = *(const s16x8*)((const char*)Bs + (wc * 64 + ni * 16 + l16) * 64 + lq * 16);
#pragma unroll
        for (int mi = 0; mi < 4; ++mi)
#pragma unroll
            for (int ni = 0; ni < 4; ++ni)
                acc[mi][ni] = mfma16(af[mi], bfr[ni], acc[mi][ni]);
    }

    // epilogue: bias + optional exact GELU; C/D layout col=lane&15, row=(lane>>4)*4+r
#pragma unroll
    for (int mi = 0; mi < 4; ++mi) {
        const int rowb = m0 + wr * 64 + mi * 16 + lq * 4;
#pragma unroll
        for (int ni = 0; ni < 4; ++ni) {
            const int col = n0 + wc * 64 + ni * 16 + l16;
            const float bv = bias[col];
#pragma unroll
            for (int r = 0; r < 4; ++r) {
                float v2 = acc[mi][ni][r] + bv;
                if (act == 1) v2 = 0.5f * v2 * (1.0f + erff(v2 * 0.70710678118654752f));
                const size_t idx = (size_t)(rowb + r) * N + col;
                if (Cf) Cf[idx] = v2;
                if (Cb) Cb[idx] = __float2bfloat16(v2);
            }
        }
    }
}

// ---------------- flash attention ----------------
// grid (qb=8, h=16, b=4), 256 threads = 4 waves; block handles 64 q-rows, wave 16 rows.
// K/V staged per 64-key tile in LDS, XOR-swizzled rows; online softmax; P via LDS.
__global__ __launch_bounds__(256) void k_attn(const __hip_bfloat16* __restrict__ qkv,
                                              const int* __restrict__ seq,
                                              const float* __restrict__ dist_emb,
                                              __hip_bfloat16* __restrict__ out) {
    const int qb = blockIdx.x, h = blockIdx.y, b = blockIdx.z;
    const int q0 = qb * 64;
    const int tid = threadIdx.x, lane = tid & 63, w = tid >> 6;
    const int l16 = lane & 15, lq = lane >> 4;

    __shared__ __align__(16) __hip_bfloat16 Ks[64 * 64];   // [key][d], swizzled
    __shared__ __align__(16) __hip_bfloat16 Vs[64 * 64];   // [d][key], swizzled
    __shared__ __align__(16) __hip_bfloat16 Ps[4 * 16 * 64]; // per-wave P, swizzled
    __shared__ float bias_l[513];
    __shared__ float pad_l[512];

    for (int i = tid; i < 513; i += 256) bias_l[i] = dist_emb[i * 16 + h];
    for (int i = tid; i < 512; i += 256) pad_l[i] = (seq[b * 512 + i] == 0) ? -1e9f : 0.0f;

    // Q fragments (A-layout: row=l16, k contiguous-8 per lq group), kept in regs
    const int qrowA = q0 + w * 16 + l16;
    const __hip_bfloat16* qptr = qkv + (size_t)(b * 512 + qrowA) * 3072 + h * 64;
    Frag8 qf[2];
    qf[0].v = *(const s16x8*)(qptr + lq * 8);
    qf[1].v = *(const s16x8*)(qptr + 32 + lq * 8);

    f32x4 oacc[4] = {};
    float mrow[4] = {-1e30f, -1e30f, -1e30f, -1e30f};
    float lrow[4] = {0.f, 0.f, 0.f, 0.f};
    char* PsW = (char*)Ps + w * 2048;

    for (int kt = 0; kt <= qb; ++kt) {
        __syncthreads();
        // stage K tile and V tile (transposed), 64x64 bf16 each
#pragma unroll
        for (int i = 0; i < 2; ++i) {
            const int c = i * 256 + tid;        // 0..511
            const int kr = c >> 3, sl = c & 7;  // key row, d-slot (8 bf16)
            const size_t srow = (size_t)(b * 512 + kt * 64 + kr) * 3072 + h * 64;
            const s16x8 kv = *(const s16x8*)(qkv + srow + 1024 + sl * 8);
            *(s16x8*)((char*)Ks + kr * 128 + ((sl ^ (kr & 7)) * 16)) = kv;
            const s16x8 vv = *(const s16x8*)(qkv + srow + 2048 + sl * 8);
#pragma unroll
            for (int j = 0; j < 8; ++j) {
                const int d = sl * 8 + j;
                *(short*)((char*)Vs + d * 128 + (((kr >> 3) ^ (d & 7)) * 16) + (kr & 7) * 2) = vv[j];
            }
        }
        __syncthreads();

        // QK^T: 16 q-rows x 64 keys
        f32x4 sacc[4] = {};
#pragma unroll
        for (int ks = 0; ks < 2; ++ks) {
#pragma unroll
            for (int nf = 0; nf < 4; ++nf) {
                const int key = nf * 16 + l16;
                Frag8 kf;
                kf.v = *(const s16x8*)((const char*)Ks + key * 128 + (((ks * 4 + lq) ^ (key & 7)) * 16));
                sacc[nf] = mfma16(qf[ks], kf, sacc[nf]);
            }
        }

        // scale + relative-distance bias + causal & pad mask
        float pvv[4][4];
#pragma unroll
        for (int nf = 0; nf < 4; ++nf) {
            const int keyg = kt * 64 + nf * 16 + l16;
            const float padv = pad_l[keyg];
#pragma unroll
            for (int r = 0; r < 4; ++r) {
                const int qg = q0 + w * 16 + lq * 4 + r;
                pvv[nf][r] = (keyg > qg) ? -1e9f
                           : sacc[nf][r] * 0.125f + bias_l[qg - keyg] + padv;
            }
        }

        // online softmax (rows owned by lane-group; reduce over 16 lanes)
#pragma unroll
        for (int r = 0; r < 4; ++r) {
            float tm = fmaxf(fmaxf(pvv[0][r], pvv[1][r]), fmaxf(pvv[2][r], pvv[3][r]));
#pragma unroll
            for (int off = 1; off < 16; off <<= 1) tm = fmaxf(tm, __shfl_xor(tm, off, 64));
            const float mnew = fmaxf(mrow[r], tm);
            const float sf = __expf(mrow[r] - mnew);
            mrow[r] = mnew;
            float ts = 0.f;
#pragma unroll
            for (int nf = 0; nf < 4; ++nf) {
                const float pe = __expf(pvv[nf][r] - mnew);
                pvv[nf][r] = pe;
                ts += pe;
            }
#pragma unroll
            for (int off = 1; off < 16; off <<= 1) ts += __shfl_xor(ts, off, 64);
            lrow[r] = lrow[r] * sf + ts;
            oacc[0][r] *= sf; oacc[1][r] *= sf; oacc[2][r] *= sf; oacc[3][r] *= sf;
        }

        // write P (D-layout) to per-wave LDS, swizzled
#pragma unroll
        for (int nf = 0; nf < 4; ++nf) {
            const int cc = nf * 16 + l16;
            const int slot = cc >> 3, rem = cc & 7;
#pragma unroll
            for (int r = 0; r < 4; ++r) {
                const int row = lq * 4 + r;
                *(short*)(PsW + row * 128 + ((slot ^ (row & 7)) * 16) + rem * 2) =
                    (short)bf16bits(pvv[nf][r]);
            }
        }
        __syncthreads();

        // PV: O += P[16x64] * V[64keys x 64d]
#pragma unroll
        for (int ks = 0; ks < 2; ++ks) {
            Frag8 pf;
            pf.v = *(const s16x8*)(PsW + l16 * 128 + (((ks * 4 + lq) ^ (l16 & 7)) * 16));
#pragma unroll
            for (int nf = 0; nf < 4; ++nf) {
                const int d = nf * 16 + l16;
                Frag8 vf;
                vf.v = *(const s16x8*)((const char*)Vs + d * 128 + (((ks * 4 + lq) ^ (d & 7)) * 16));
                oacc[nf] = mfma16(pf, vf, oacc[nf]);
            }
        }
    }

    // epilogue: out[b, q, h*64+d] = O/l
#pragma unroll
    for (int nf = 0; nf < 4; ++nf) {
        const int d = nf * 16 + l16;
#pragma unroll
        for (int r = 0; r < 4; ++r) {
            const int qg = q0 + w * 16 + lq * 4 + r;
            out[(size_t)(b * 512 + qg) * 1024 + h * 64 + d] = __float2bfloat16(oacc[nf][r] / lrow[r]);
        }
    }
}

// ---------------- fused residual add + LayerNorm ----------------
__global__ __launch_bounds__(256) void k_add_ln(const float* __restrict__ x,
                                                const float* __restrict__ res,
                                                const float* __restrict__ gamma,
                                                const float* __restrict__ beta,
                                                float* __restrict__ xout,
                                                __hip_bfloat16* __restrict__ bout) {
    const int t = blockIdx.x;
    const int tid = threadIdx.x;
    float4 y = *(const float4*)(x + (size_t)t * 1024 + tid * 4);
    if (res) {
        const float4 rv = *(const float4*)(res + (size_t)t * 1024 + tid * 4);
        y.x += rv.x; y.y += rv.y; y.z += rv.z; y.w += rv.w;
    }
    float s = y.x + y.y + y.z + y.w;
    float s2 = y.x * y.x + y.y * y.y + y.z * y.z + y.w * y.w;
#pragma unroll
    for (int off = 32; off >= 1; off >>= 1) {
        s += __shfl_xor(s, off, 64);
        s2 += __shfl_xor(s2, off, 64);
    }
    __shared__ float red[8];
    const int w = tid >> 6, lane = tid & 63;
    if (lane == 0) { red[w] = s; red[4 + w] = s2; }
    __syncthreads();
    const float tot = red[0] + red[1] + red[2] + red[3];
    const float tot2 = red[4] + red[5] + red[6] + red[7];
    const float mean = tot * (1.0f / 1024.0f);
    const float var = tot2 * (1.0f / 1024.0f) - mean * mean;
    const float inv = rsqrtf(var + 1e-5f);
    const float4 g = *(const float4*)(gamma + tid * 4);
    const float4 bb = *(const float4*)(beta + tid * 4);
    float4 o;
    o.x = (y.x - mean) * inv * g.x + bb.x;
    o.y = (y.y - mean) * inv * g.y + bb.y;
    o.z = (y.z - mean) * inv * g.z + bb.z;
    o.w = (y.w - mean) * inv * g.w + bb.w;
    *(float4*)(xout + (size_t)t * 1024 + tid * 4) = o;
    ushort4 u;
    u.x = bf16bits(o.x); u.y = bf16bits(o.y); u.z = bf16bits(o.z); u.w = bf16bits(o.w);
    *(ushort4*)((unsigned short*)bout + (size_t)t * 1024 + tid * 4) = u;
}

// ---------------- host ----------------
extern "C" void kernel_launch(void* const* d_in, const int* in_sizes, int n_in,
                              void* d_out, int out_size, void* d_ws, size_t ws_size,
                              hipStream_t stream) {
    const int* seq = (const int*)d_in[0];
    const float* tok = (const float*)d_in[1];
    const float* dist = (const float*)d_in[2];
    const float* Wqkv = (const float*)d_in[3];
    const float* bqkv = (const float*)d_in[4];
    const float* Wo = (const float*)d_in[5];
    const float* bo = (const float*)d_in[6];
    const float* W1 = (const float*)d_in[7];
    const float* b1 = (const float*)d_in[8];
    const float* W2 = (const float*)d_in[9];
    const float* b2 = (const float*)d_in[10];
    const float* ln1s = (const float*)d_in[11];
    const float* ln1b = (const float*)d_in[12];
    const float* ln2s = (const float*)d_in[13];
    const float* ln2b = (const float*)d_in[14];
    const float* lnfs = (const float*)d_in[15];
    const float* lnfb = (const float*)d_in[16];
    const float* Wg = (const float*)d_in[17];
    const float* bg = (const float*)d_in[18];
    float* out = (float*)d_out;

    char* p = (char*)d_ws;
    auto take = [&](size_t bytes) {
        char* r = p;
        p += (bytes + 255) & ~(size_t)255;
        return r;
    };
    __hip_bfloat16* wqkv_b = (__hip_bfloat16*)take((size_t)6 * 3072 * 1024 * 2);
    __hip_bfloat16* wo_b = (__hip_bfloat16*)take((size_t)6 * 1024 * 1024 * 2);
    __hip_bfloat16* w1_b = (__hip_bfloat16*)take((size_t)6 * 4096 * 1024 * 2);
    __hip_bfloat16* w2_b = (__hip_bfloat16*)take((size_t)6 * 1024 * 4096 * 2);
    __hip_bfloat16* wg_b = (__hip_bfloat16*)take((size_t)32000 * 1024 * 2);
    float* xf = (float*)take((size_t)2048 * 1024 * 4);
    __hip_bfloat16* xb = (__hip_bfloat16*)take((size_t)2048 * 1024 * 2);
    __hip_bfloat16* qkvb = (__hip_bfloat16*)take((size_t)2048 * 3072 * 2);
    __hip_bfloat16* hb = (__hip_bfloat16*)take((size_t)2048 * 4096 * 2);
    __hip_bfloat16* ab = (__hip_bfloat16*)take((size_t)2048 * 1024 * 2);
    float* tmpf = (float*)take((size_t)2048 * 1024 * 4);

    auto conv = [&](const float* src, __hip_bfloat16* dst, long n) {
        k_f32_to_bf16<<<dim3((unsigned)(n / 1024)), dim3(256), 0, stream>>>(src, dst, n);
    };
    conv(Wqkv, wqkv_b, (long)6 * 3072 * 1024);
    conv(Wo, wo_b, (long)6 * 1024 * 1024);
    conv(W1, w1_b, (long)6 * 4096 * 1024);
    conv(W2, w2_b, (long)6 * 1024 * 4096);
    conv(Wg, wg_b, (long)32000 * 1024);

    k_embed<<<dim3(2048), dim3(256), 0, stream>>>(seq, tok, xf, xb);

    for (int l = 0; l < 6; ++l) {
        k_gemm_bt<<<dim3(24, 16), dim3(256), 0, stream>>>(
            xb, wqkv_b + (size_t)l * 3072 * 1024, bqkv + l * 3072, nullptr, qkvb,
            2048, 3072, 1024, 0);
        k_attn<<<dim3(8, 16, 4), dim3(256), 0, stream>>>(qkvb, seq, dist, ab);
        k_gemm_bt<<<dim3(8, 16), dim3(256), 0, stream>>>(
            ab, wo_b + (size_t)l * 1024 * 1024, bo + l * 1024, tmpf, nullptr,
            2048, 1024, 1024, 0);
        k_add_ln<<<dim3(2048), dim3(256), 0, stream>>>(xf, tmpf, ln1s + l * 1024,
                                                       ln1b + l * 1024, xf, xb);
        k_gemm_bt<<<dim3(32, 16), dim3(256), 0, stream>>>(
            xb, w1_b + (size_t)l * 4096 * 1024, b1 + l * 4096, nullptr, hb,
            2048, 4096, 1024, 1);
        k_gemm_bt<<<dim3(8, 16), dim3(256), 0, stream>>>(
            hb, w2_b + (size_t)l * 1024 * 4096, b2 + l * 1024, tmpf, nullptr,
            2048, 1024, 4096, 0);
        k_add_ln<<<dim3(2048), dim3(256), 0, stream>>>(xf, tmpf, ln2s + l * 1024,
                                                       ln2b + l * 1024, xf, xb);
    }
    k_add_ln<<<dim3(2048), dim3(256), 0, stream>>>(xf, nullptr, lnfs, lnfb, xf, xb);
    k_gemm_bt<<<dim3(250, 16), dim3(256), 0, stream>>>(xb, wg_b, bg, out, nullptr,
                                                       2048, 32000, 1024, 0);
}

// Round 2
// 1688.275 us; speedup vs baseline: 1.1250x; 1.1250x over previous
//
#include <hip/hip_runtime.h>
#include <hip/hip_bf16.h>
#include <cstdint>

// Problem dims
// L=6, E=1024, H=16, F=4096, V=32000, B=4, S=512, ML=512, DH=64, tokens=2048

typedef float f32x4 __attribute__((ext_vector_type(4)));
typedef short s16x8 __attribute__((ext_vector_type(8)));
typedef __bf16 b16x8 __attribute__((ext_vector_type(8)));

struct Frag8 {
    s16x8 v;
    __device__ operator s16x8() const { return v; }
    __device__ operator b16x8() const { return __builtin_bit_cast(b16x8, v); }
};

__device__ __forceinline__ f32x4 mfma16(Frag8 a, Frag8 b, f32x4 c) {
    return __builtin_amdgcn_mfma_f32_16x16x32_bf16(a, b, c, 0, 0, 0);
}

__device__ __forceinline__ void gload_lds16(const void* g, void* l) {
    __builtin_amdgcn_global_load_lds(
        (__attribute__((address_space(1))) void*)g,
        (__attribute__((address_space(3))) void*)l, 16, 0, 0);
}

__device__ __forceinline__ unsigned short bf16bits(float x) {
    return __builtin_bit_cast(unsigned short, __float2bfloat16(x));
}

// ---------------- fp32 -> bf16 conversion ----------------
__global__ __launch_bounds__(256) void k_f32_to_bf16(const float* __restrict__ in,
                                                     __hip_bfloat16* __restrict__ out,
                                                     long n) {
    const long i = ((long)blockIdx.x * 256 + threadIdx.x) * 4;
    if (i >= n) return;
    const float4 v = *(const float4*)(in + i);
    ushort4 u;
    u.x = bf16bits(v.x); u.y = bf16bits(v.y); u.z = bf16bits(v.z); u.w = bf16bits(v.w);
    *(ushort4*)((unsigned short*)out + i) = u;
}

// ---------------- embedding gather ----------------
__global__ __launch_bounds__(256) void k_embed(const int* __restrict__ seq,
                                               const float* __restrict__ tok,
                                               float* __restrict__ x,
                                               __hip_bfloat16* __restrict__ xb) {
    const int t = blockIdx.x;
    const int tokid = seq[t];
    const float4 v = *(const float4*)(tok + (size_t)tokid * 1024 + threadIdx.x * 4);
    float4 o;
    o.x = v.x * 32.0f; o.y = v.y * 32.0f; o.z = v.z * 32.0f; o.w = v.w * 32.0f;
    *(float4*)(x + (size_t)t * 1024 + threadIdx.x * 4) = o;
    ushort4 u;
    u.x = bf16bits(o.x); u.y = bf16bits(o.y); u.z = bf16bits(o.z); u.w = bf16bits(o.w);
    *(ushort4*)((unsigned short*)xb + (size_t)t * 1024 + threadIdx.x * 4) = u;
}

// ---------------- GEMM: C[M,N] = A[M,K] * B[N,K]^T (+bias, optional GELU) ----------------
// 128x128 tile, BK=32, 4 waves each computing a 64x64 quadrant as 4x4 MFMA frags.
// 1D grid.x = (M/128)*(N/128), m-tile fastest + bijective XCD swizzle.
// grid.y = split-K index; each split writes its own M*N f32 partial (bias only in part 0).
__global__ __launch_bounds__(256) void k_gemm_bt(const __hip_bfloat16* __restrict__ A,
                                                 const __hip_bfloat16* __restrict__ B,
                                                 const float* __restrict__ bias,
                                                 float* __restrict__ Cf,
                                                 __hip_bfloat16* __restrict__ Cb,
                                                 const int M, const int N, const int K,
                                                 const int Ksub, const int mtiles,
                                                 const int act) {
    __shared__ __align__(16) __hip_bfloat16 As[128 * 32];
    __shared__ __align__(16) __hip_bfloat16 Bs[128 * 32];

    // bijective XCD-aware remap (nwg % 8 == 0 in all our launches, but keep general)
    const int nwg = gridDim.x;
    const int bid = blockIdx.x;
    const int q = nwg >> 3, r = nwg & 7;
    const int xcd = bid & 7, local = bid >> 3;
    const int wgid = (xcd < r ? xcd * (q + 1) : r * (q + 1) + (xcd - r) * q) + local;
    const int m0 = (wgid % mtiles) * 128;
    const int n0 = (wgid / mtiles) * 128;

    const int tid = threadIdx.x;
    const int lane = tid & 63, w = tid >> 6;
    const int wr = w >> 1, wc = w & 1;
    const int l16 = lane & 15, lq = lane >> 4;

    const int kb = blockIdx.y * Ksub;

    f32x4 acc[4][4] = {};

    for (int k0 = kb; k0 < kb + Ksub; k0 += 32) {
        __syncthreads();
#pragma unroll
        for (int i = 0; i < 2; ++i) {
            const int c = i * 256 + tid;          // 0..511 16B-chunks
            const int row = c >> 2, sl = c & 3;   // [row][sl*8 .. sl*8+7]
            gload_lds16(A + (size_t)(m0 + row) * K + k0 + sl * 8, (char*)As + c * 16);
            gload_lds16(B + (size_t)(n0 + row) * K + k0 + sl * 8, (char*)Bs + c * 16);
        }
        __syncthreads();

        Frag8 af[4], bfr[4];
#pragma unroll
        for (int mi = 0; mi < 4; ++mi)
            af[mi].v = *(const s16x8*)((const char*)As + (wr * 64 + mi * 16 + l16) * 64 + lq * 16);
#pragma unroll
        for (int ni = 0; ni < 4; ++ni)
            bfr[ni].v = *(const s16x8*)((const char*)Bs + (wc * 64 + ni * 16 + l16) * 64 + lq * 16);
#pragma unroll
        for (int mi = 0; mi < 4; ++mi)
#pragma unroll
            for (int ni = 0; ni < 4; ++ni)
                acc[mi][ni] = mfma16(af[mi], bfr[ni], acc[mi][ni]);
    }

    float* Cfp = Cf ? Cf + (size_t)blockIdx.y * M * N : nullptr;
    const bool addb = (blockIdx.y == 0);

    // epilogue: C/D layout col=lane&15, row=(lane>>4)*4+r
#pragma unroll
    for (int mi = 0; mi < 4; ++mi) {
        const int rowb = m0 + wr * 64 + mi * 16 + lq * 4;
#pragma unroll
        for (int ni = 0; ni < 4; ++ni) {
            const int col = n0 + wc * 64 + ni * 16 + l16;
            const float bv = addb ? bias[col] : 0.0f;
#pragma unroll
            for (int r = 0; r < 4; ++r) {
                float v2 = acc[mi][ni][r] + bv;
                if (act == 1) v2 = 0.5f * v2 * (1.0f + erff(v2 * 0.70710678118654752f));
                const size_t idx = (size_t)(rowb + r) * N + col;
                if (Cfp) Cfp[idx] = v2;
                if (Cb) Cb[idx] = __float2bfloat16(v2);
            }
        }
    }
}

// ---------------- flash attention ----------------
__global__ __launch_bounds__(256) void k_attn(const __hip_bfloat16* __restrict__ qkv,
                                              const int* __restrict__ seq,
                                              const float* __restrict__ dist_emb,
                                              __hip_bfloat16* __restrict__ out) {
    const int qb = blockIdx.x, h = blockIdx.y, b = blockIdx.z;
    const int q0 = qb * 64;
    const int tid = threadIdx.x, lane = tid & 63, w = tid >> 6;
    const int l16 = lane & 15, lq = lane >> 4;

    __shared__ __align__(16) __hip_bfloat16 Ks[64 * 64];
    __shared__ __align__(16) __hip_bfloat16 Vs[64 * 64];
    __shared__ __align__(16) __hip_bfloat16 Ps[4 * 16 * 64];
    __shared__ float bias_l[513];
    __shared__ float pad_l[512];

    for (int i = tid; i < 513; i += 256) bias_l[i] = dist_emb[i * 16 + h];
    for (int i = tid; i < 512; i += 256) pad_l[i] = (seq[b * 512 + i] == 0) ? -1e9f : 0.0f;

    const int qrowA = q0 + w * 16 + l16;
    const __hip_bfloat16* qptr = qkv + (size_t)(b * 512 + qrowA) * 3072 + h * 64;
    Frag8 qf[2];
    qf[0].v = *(const s16x8*)(qptr + lq * 8);
    qf[1].v = *(const s16x8*)(qptr + 32 + lq * 8);

    f32x4 oacc[4] = {};
    float mrow[4] = {-1e30f, -1e30f, -1e30f, -1e30f};
    float lrow[4] = {0.f, 0.f, 0.f, 0.f};
    char* PsW = (char*)Ps + w * 2048;

    for (int kt = 0; kt <= qb; ++kt) {
        __syncthreads();
#pragma unroll
        for (int i = 0; i < 2; ++i) {
            const int c = i * 256 + tid;
            const int kr = c >> 3, sl = c & 7;
            const size_t srow = (size_t)(b * 512 + kt * 64 + kr) * 3072 + h * 64;
            const s16x8 kv = *(const s16x8*)(qkv + srow + 1024 + sl * 8);
            *(s16x8*)((char*)Ks + kr * 128 + ((sl ^ (kr & 7)) * 16)) = kv;
            const s16x8 vv = *(const s16x8*)(qkv + srow + 2048 + sl * 8);
#pragma unroll
            for (int j = 0; j < 8; ++j) {
                const int d = sl * 8 + j;
                *(short*)((char*)Vs + d * 128 + (((kr >> 3) ^ (d & 7)) * 16) + (kr & 7) * 2) = vv[j];
            }
        }
        __syncthreads();

        f32x4 sacc[4] = {};
#pragma unroll
        for (int ks = 0; ks < 2; ++ks) {
#pragma unroll
            for (int nf = 0; nf < 4; ++nf) {
                const int key = nf * 16 + l16;
                Frag8 kf;
                kf.v = *(const s16x8*)((const char*)Ks + key * 128 + (((ks * 4 + lq) ^ (key & 7)) * 16));
                sacc[nf] = mfma16(qf[ks], kf, sacc[nf]);
            }
        }

        float pvv[4][4];
#pragma unroll
        for (int nf = 0; nf < 4; ++nf) {
            const int keyg = kt * 64 + nf * 16 + l16;
            const float padv = pad_l[keyg];
#pragma unroll
            for (int r = 0; r < 4; ++r) {
                const int qg = q0 + w * 16 + lq * 4 + r;
                pvv[nf][r] = (keyg > qg) ? -1e9f
                           : sacc[nf][r] * 0.125f + bias_l[qg - keyg] + padv;
            }
        }

#pragma unroll
        for (int r = 0; r < 4; ++r) {
            float tm = fmaxf(fmaxf(pvv[0][r], pvv[1][r]), fmaxf(pvv[2][r], pvv[3][r]));
#pragma unroll
            for (int off = 1; off < 16; off <<= 1) tm = fmaxf(tm, __shfl_xor(tm, off, 64));
            const float mnew = fmaxf(mrow[r], tm);
            const float sf = __expf(mrow[r] - mnew);
            mrow[r] = mnew;
            float ts = 0.f;
#pragma unroll
            for (int nf = 0; nf < 4; ++nf) {
                const float pe = __expf(pvv[nf][r] - mnew);
                pvv[nf][r] = pe;
                ts += pe;
            }
#pragma unroll
            for (int off = 1; off < 16; off <<= 1) ts += __shfl_xor(ts, off, 64);
            lrow[r] = lrow[r] * sf + ts;
            oacc[0][r] *= sf; oacc[1][r] *= sf; oacc[2][r] *= sf; oacc[3][r] *= sf;
        }

#pragma unroll
        for (int nf = 0; nf < 4; ++nf) {
            const int cc = nf * 16 + l16;
            const int slot = cc >> 3, rem = cc & 7;
#pragma unroll
            for (int r = 0; r < 4; ++r) {
                const int row = lq * 4 + r;
                *(short*)(PsW + row * 128 + ((slot ^ (row & 7)) * 16) + rem * 2) =
                    (short)bf16bits(pvv[nf][r]);
            }
        }
        __syncthreads();

#pragma unroll
        for (int ks = 0; ks < 2; ++ks) {
            Frag8 pf;
            pf.v = *(const s16x8*)(PsW + l16 * 128 + (((ks * 4 + lq) ^ (l16 & 7)) * 16));
#pragma unroll
            for (int nf = 0; nf < 4; ++nf) {
                const int d = nf * 16 + l16;
                Frag8 vf;
                vf.v = *(const s16x8*)((const char*)Vs + d * 128 + (((ks * 4 + lq) ^ (d & 7)) * 16));
                oacc[nf] = mfma16(pf, vf, oacc[nf]);
            }
        }
    }

#pragma unroll
    for (int nf = 0; nf < 4; ++nf) {
        const int d = nf * 16 + l16;
#pragma unroll
        for (int r = 0; r < 4; ++r) {
            const int qg = q0 + w * 16 + lq * 4 + r;
            out[(size_t)(b * 512 + qg) * 1024 + h * 64 + d] = __float2bfloat16(oacc[nf][r] / lrow[r]);
        }
    }
}

// ---------------- fused residual add (up to 2 partials) + LayerNorm ----------------
__global__ __launch_bounds__(256) void k_add_ln(const float* __restrict__ x,
                                                const float* __restrict__ res0,
                                                const float* __restrict__ res1,
                                                const float* __restrict__ gamma,
                                                const float* __restrict__ beta,
                                                float* __restrict__ xout,
                                                __hip_bfloat16* __restrict__ bout) {
    const int t = blockIdx.x;
    const int tid = threadIdx.x;
    float4 y = *(const float4*)(x + (size_t)t * 1024 + tid * 4);
    if (res0) {
        const float4 rv = *(const float4*)(res0 + (size_t)t * 1024 + tid * 4);
        y.x += rv.x; y.y += rv.y; y.z += rv.z; y.w += rv.w;
    }
    if (res1) {
        const float4 rv = *(const float4*)(res1 + (size_t)t * 1024 + tid * 4);
        y.x += rv.x; y.y += rv.y; y.z += rv.z; y.w += rv.w;
    }
    float s = y.x + y.y + y.z + y.w;
    float s2 = y.x * y.x + y.y * y.y + y.z * y.z + y.w * y.w;
#pragma unroll
    for (int off = 32; off >= 1; off >>= 1) {
        s += __shfl_xor(s, off, 64);
        s2 += __shfl_xor(s2, off, 64);
    }
    __shared__ float red[8];
    const int w = tid >> 6, lane = tid & 63;
    if (lane == 0) { red[w] = s; red[4 + w] = s2; }
    __syncthreads();
    const float tot = red[0] + red[1] + red[2] + red[3];
    const float tot2 = red[4] + red[5] + red[6] + red[7];
    const float mean = tot * (1.0f / 1024.0f);
    const float var = tot2 * (1.0f / 1024.0f) - mean * mean;
    const float inv = rsqrtf(var + 1e-5f);
    const float4 g = *(const float4*)(gamma + tid * 4);
    const float4 bb = *(const float4*)(beta + tid * 4);
    float4 o;
    o.x = (y.x - mean) * inv * g.x + bb.x;
    o.y = (y.y - mean) * inv * g.y + bb.y;
    o.z = (y.z - mean) * inv * g.z + bb.z;
    o.w = (y.w - mean) * inv * g.w + bb.w;
    *(float4*)(xout + (size_t)t * 1024 + tid * 4) = o;
    ushort4 u;
    u.x = bf16bits(o.x); u.y = bf16bits(o.y); u.z = bf16bits(o.z); u.w = bf16bits(o.w);
    *(ushort4*)((unsigned short*)bout + (size_t)t * 1024 + tid * 4) = u;
}

// ---------------- host ----------------
extern "C" void kernel_launch(void* const* d_in, const int* in_sizes, int n_in,
                              void* d_out, int out_size, void* d_ws, size_t ws_size,
                              hipStream_t stream) {
    const int* seq = (const int*)d_in[0];
    const float* tok = (const float*)d_in[1];
    const float* dist = (const float*)d_in[2];
    const float* Wqkv = (const float*)d_in[3];
    const float* bqkv = (const float*)d_in[4];
    const float* Wo = (const float*)d_in[5];
    const float* bo = (const float*)d_in[6];
    const float* W1 = (const float*)d_in[7];
    const float* b1 = (const float*)d_in[8];
    const float* W2 = (const float*)d_in[9];
    const float* b2 = (const float*)d_in[10];
    const float* ln1s = (const float*)d_in[11];
    const float* ln1b = (const float*)d_in[12];
    const float* ln2s = (const float*)d_in[13];
    const float* ln2b = (const float*)d_in[14];
    const float* lnfs = (const float*)d_in[15];
    const float* lnfb = (const float*)d_in[16];
    const float* Wg = (const float*)d_in[17];
    const float* bg = (const float*)d_in[18];
    float* out = (float*)d_out;

    char* p = (char*)d_ws;
    auto take = [&](size_t bytes) {
        char* r = p;
        p += (bytes + 255) & ~(size_t)255;
        return r;
    };
    __hip_bfloat16* wqkv_b = (__hip_bfloat16*)take((size_t)6 * 3072 * 1024 * 2);
    __hip_bfloat16* wo_b = (__hip_bfloat16*)take((size_t)6 * 1024 * 1024 * 2);
    __hip_bfloat16* w1_b = (__hip_bfloat16*)take((size_t)6 * 4096 * 1024 * 2);
    __hip_bfloat16* w2_b = (__hip_bfloat16*)take((size_t)6 * 1024 * 4096 * 2);
    __hip_bfloat16* wg_b = (__hip_bfloat16*)take((size_t)32000 * 1024 * 2);
    float* xf = (float*)take((size_t)2048 * 1024 * 4);
    __hip_bfloat16* xb = (__hip_bfloat16*)take((size_t)2048 * 1024 * 2);
    __hip_bfloat16* qkvb = (__hip_bfloat16*)take((size_t)2048 * 3072 * 2);
    __hip_bfloat16* hb = (__hip_bfloat16*)take((size_t)2048 * 4096 * 2);
    __hip_bfloat16* ab = (__hip_bfloat16*)take((size_t)2048 * 1024 * 2);
    float* tmpf = (float*)take((size_t)2 * 2048 * 1024 * 4);  // 2 split-K partials
    float* tmpf1 = tmpf + (size_t)2048 * 1024;

    auto conv = [&](const float* src, __hip_bfloat16* dst, long n) {
        k_f32_to_bf16<<<dim3((unsigned)(n / 1024)), dim3(256), 0, stream>>>(src, dst, n);
    };
    conv(Wqkv, wqkv_b, (long)6 * 3072 * 1024);
    conv(Wo, wo_b, (long)6 * 1024 * 1024);
    conv(W1, w1_b, (long)6 * 4096 * 1024);
    conv(W2, w2_b, (long)6 * 1024 * 4096);
    conv(Wg, wg_b, (long)32000 * 1024);

    k_embed<<<dim3(2048), dim3(256), 0, stream>>>(seq, tok, xf, xb);

    for (int l = 0; l < 6; ++l) {
        // QKV: 2048 x 3072 x 1024, bf16 out
        k_gemm_bt<<<dim3(16 * 24), dim3(256), 0, stream>>>(
            xb, wqkv_b + (size_t)l * 3072 * 1024, bqkv + l * 3072, nullptr, qkvb,
            2048, 3072, 1024, 1024, 16, 0);
        k_attn<<<dim3(8, 16, 4), dim3(256), 0, stream>>>(qkvb, seq, dist, ab);
        // Wo: 2048 x 1024 x 1024, split-K=2 -> f32 partials
        k_gemm_bt<<<dim3(16 * 8, 2), dim3(256), 0, stream>>>(
            ab, wo_b + (size_t)l * 1024 * 1024, bo + l * 1024, tmpf, nullptr,
            2048, 1024, 1024, 512, 16, 0);
        k_add_ln<<<dim3(2048), dim3(256), 0, stream>>>(xf, tmpf, tmpf1, ln1s + l * 1024,
                                                       ln1b + l * 1024, xf, xb);
        // FFN1: 2048 x 4096 x 1024, GELU, bf16 out
        k_gemm_bt<<<dim3(16 * 32), dim3(256), 0, stream>>>(
            xb, w1_b + (size_t)l * 4096 * 1024, b1 + l * 4096, nullptr, hb,
            2048, 4096, 1024, 1024, 16, 1);
        // FFN2: 2048 x 1024 x 4096, split-K=2 -> f32 partials
        k_gemm_bt<<<dim3(16 * 8, 2), dim3(256), 0, stream>>>(
            hb, w2_b + (size_t)l * 1024 * 4096, b2 + l * 1024, tmpf, nullptr,
            2048, 1024, 4096, 2048, 16, 0);
        k_add_ln<<<dim3(2048), dim3(256), 0, stream>>>(xf, tmpf, tmpf1, ln2s + l * 1024,
                                                       ln2b + l * 1024, xf, xb);
    }
    k_add_ln<<<dim3(2048), dim3(256), 0, stream>>>(xf, nullptr, nullptr, lnfs, lnfb, xf, xb);
    // vocab: 2048 x 32000 x 1024, f32 out
    k_gemm_bt<<<dim3(16 * 250), dim3(256), 0, stream>>>(xb, wg_b, bg, out, nullptr,
                                                        2048, 32000, 1024, 1024, 16, 0);
}

// Round 3
// 1432.488 us; speedup vs baseline: 1.3258x; 1.1786x over previous
//
#include <hip/hip_runtime.h>
#include <hip/hip_bf16.h>
#include <cstdint>

// Problem dims
// L=6, E=1024, H=16, F=4096, V=32000, B=4, S=512, ML=512, DH=64, tokens=2048

typedef float f32x4 __attribute__((ext_vector_type(4)));
typedef short s16x8 __attribute__((ext_vector_type(8)));
typedef __bf16 b16x8 __attribute__((ext_vector_type(8)));

struct Frag8 {
    s16x8 v;
    __device__ operator s16x8() const { return v; }
    __device__ operator b16x8() const { return __builtin_bit_cast(b16x8, v); }
};

__device__ __forceinline__ f32x4 mfma16(Frag8 a, Frag8 b, f32x4 c) {
    return __builtin_amdgcn_mfma_f32_16x16x32_bf16(a, b, c, 0, 0, 0);
}

__device__ __forceinline__ void gload_lds16(const void* g, void* l) {
    __builtin_amdgcn_global_load_lds(
        (__attribute__((address_space(1))) void*)g,
        (__attribute__((address_space(3))) void*)l, 16, 0, 0);
}

__device__ __forceinline__ unsigned short bf16bits(float x) {
    return __builtin_bit_cast(unsigned short, __float2bfloat16(x));
}

// swizzled LDS fragment pointer: tile stored as row-pair 128B lines,
// within-line 16B slot u = ((row&1)<<2)|lq, stored at slot u ^ (line&7).
__device__ __forceinline__ const s16x8* fragp(const char* base, int row, int lq) {
    const int line = row >> 1;
    const int u = ((row & 1) << 2) | lq;
    return (const s16x8*)(base + line * 128 + ((u ^ (line & 7)) << 4));
}

// ---------------- fp32 -> bf16 conversion ----------------
__global__ __launch_bounds__(256) void k_f32_to_bf16(const float* __restrict__ in,
                                                     __hip_bfloat16* __restrict__ out,
                                                     long n) {
    const long i = ((long)blockIdx.x * 256 + threadIdx.x) * 4;
    if (i >= n) return;
    const float4 v = *(const float4*)(in + i);
    ushort4 u;
    u.x = bf16bits(v.x); u.y = bf16bits(v.y); u.z = bf16bits(v.z); u.w = bf16bits(v.w);
    *(ushort4*)((unsigned short*)out + i) = u;
}

// ---------------- embedding gather ----------------
__global__ __launch_bounds__(256) void k_embed(const int* __restrict__ seq,
                                               const float* __restrict__ tok,
                                               float* __restrict__ x,
                                               __hip_bfloat16* __restrict__ xb) {
    const int t = blockIdx.x;
    const int tokid = seq[t];
    const float4 v = *(const float4*)(tok + (size_t)tokid * 1024 + threadIdx.x * 4);
    float4 o;
    o.x = v.x * 32.0f; o.y = v.y * 32.0f; o.z = v.z * 32.0f; o.w = v.w * 32.0f;
    *(float4*)(x + (size_t)t * 1024 + threadIdx.x * 4) = o;
    ushort4 u;
    u.x = bf16bits(o.x); u.y = bf16bits(o.y); u.z = bf16bits(o.z); u.w = bf16bits(o.w);
    *(ushort4*)((unsigned short*)xb + (size_t)t * 1024 + threadIdx.x * 4) = u;
}

// ---------------- pipelined GEMM: C[M,N] = A[M,K] * B[N,K]^T (+bias, opt GELU) ----
// 128x128 tile, BK=32, 4 waves (2x2), triple-buffered LDS staged 2 K-tiles ahead,
// one s_barrier + counted vmcnt(4) per K-tile, swizzled conflict-free ds_read_b128.
// TAG only differentiates kernel names for profiling.
template <int TAG>
__global__ __launch_bounds__(256, 2) void k_gemm(const __hip_bfloat16* __restrict__ A,
                                                 const __hip_bfloat16* __restrict__ B,
                                                 const float* __restrict__ bias,
                                                 float* __restrict__ Cf,
                                                 __hip_bfloat16* __restrict__ Cb,
                                                 const int M, const int N, const int K,
                                                 const int Ksub, const int mtiles,
                                                 const int act) {
    __shared__ __align__(16) char lds[3 * 16384];  // [buf][A 8KB | B 8KB]

    // bijective XCD-aware remap, m-tile fastest (B-panel L2 reuse)
    const int nwg = gridDim.x;
    const int bid = blockIdx.x;
    const int q = nwg >> 3, r = nwg & 7;
    const int xcd = bid & 7, local = bid >> 3;
    const int wgid = (xcd < r ? xcd * (q + 1) : r * (q + 1) + (xcd - r) * q) + local;
    const int m0 = (wgid % mtiles) * 128;
    const int n0 = (wgid / mtiles) * 128;

    const int tid = threadIdx.x;
    const int lane = tid & 63, w = tid >> 6;
    const int wr = w >> 1, wc = w & 1;
    const int l16 = lane & 15, lq = lane >> 4;

    const int kb = blockIdx.y * Ksub;
    const int NT = Ksub >> 5;

    // staging source mapping (inverse swizzle) for chunks c0=tid, c1=tid+256
    int arow0, acol0, arow1, acol1;
    {
        const int c0 = tid, line0 = c0 >> 3, u0 = (c0 & 7) ^ (line0 & 7);
        arow0 = (line0 << 1) | (u0 >> 2); acol0 = (u0 & 3) * 8;
        const int c1 = tid + 256, line1 = c1 >> 3, u1 = (c1 & 7) ^ (line1 & 7);
        arow1 = (line1 << 1) | (u1 >> 2); acol1 = (u1 & 3) * 8;
    }
    const size_t abase0 = (size_t)(m0 + arow0) * K + acol0 + kb;
    const size_t abase1 = (size_t)(m0 + arow1) * K + acol1 + kb;
    const size_t bbase0 = (size_t)(n0 + arow0) * K + acol0 + kb;
    const size_t bbase1 = (size_t)(n0 + arow1) * K + acol1 + kb;

    auto stageA = [&](int tt, int buf) {
        char* dst = lds + buf * 16384;
        gload_lds16(A + abase0 + tt * 32, dst + tid * 16);
        gload_lds16(A + abase1 + tt * 32, dst + (tid + 256) * 16);
    };
    auto stageB = [&](int tt, int buf) {
        char* dst = lds + buf * 16384 + 8192;
        gload_lds16(B + bbase0 + tt * 32, dst + tid * 16);
        gload_lds16(B + bbase1 + tt * 32, dst + (tid + 256) * 16);
    };

    f32x4 acc[4][4] = {};

    // prologue: stage tiles 0,1; wait tile 0 (leave tile 1's 4 loads in flight)
    stageA(0, 0); stageB(0, 0);
    stageA(1, 1); stageB(1, 1);
    asm volatile("s_waitcnt vmcnt(4)" ::: "memory");
    __builtin_amdgcn_sched_barrier(0);
    __builtin_amdgcn_s_barrier();
    __builtin_amdgcn_sched_barrier(0);

    int cur = 0;
    for (int t = 0; t < NT; ++t) {
        const int stb = (cur == 0) ? 2 : cur - 1;  // (t+2)%3
        const char* Ab = lds + cur * 16384;
        const char* Bb = Ab + 8192;
        const bool doStage = (t + 2 < NT);

        if (doStage) stageA(t + 2, stb);

        Frag8 a0, a1, b0, b1, b2, b3;
        a0.v = *fragp(Ab, wr * 64 + l16, lq);
        a1.v = *fragp(Ab, wr * 64 + 16 + l16, lq);
        b0.v = *fragp(Bb, wc * 64 + l16, lq);
        b1.v = *fragp(Bb, wc * 64 + 16 + l16, lq);
        b2.v = *fragp(Bb, wc * 64 + 32 + l16, lq);
        b3.v = *fragp(Bb, wc * 64 + 48 + l16, lq);

        __builtin_amdgcn_s_setprio(1);
        acc[0][0] = mfma16(a0, b0, acc[0][0]);
        acc[0][1] = mfma16(a0, b1, acc[0][1]);
        acc[0][2] = mfma16(a0, b2, acc[0][2]);
        acc[0][3] = mfma16(a0, b3, acc[0][3]);
        acc[1][0] = mfma16(a1, b0, acc[1][0]);
        acc[1][1] = mfma16(a1, b1, acc[1][1]);
        acc[1][2] = mfma16(a1, b2, acc[1][2]);
        acc[1][3] = mfma16(a1, b3, acc[1][3]);
        __builtin_amdgcn_s_setprio(0);

        if (doStage) stageB(t + 2, stb);

        Frag8 a2, a3;
        a2.v = *fragp(Ab, wr * 64 + 32 + l16, lq);
        a3.v = *fragp(Ab, wr * 64 + 48 + l16, lq);

        __builtin_amdgcn_s_setprio(1);
        acc[2][0] = mfma16(a2, b0, acc[2][0]);
        acc[2][1] = mfma16(a2, b1, acc[2][1]);
        acc[2][2] = mfma16(a2, b2, acc[2][2]);
        acc[2][3] = mfma16(a2, b3, acc[2][3]);
        acc[3][0] = mfma16(a3, b0, acc[3][0]);
        acc[3][1] = mfma16(a3, b1, acc[3][1]);
        acc[3][2] = mfma16(a3, b2, acc[3][2]);
        acc[3][3] = mfma16(a3, b3, acc[3][3]);
        __builtin_amdgcn_s_setprio(0);

        // once per K-tile: counted wait (guarantees tile t+1 landed), collective barrier
        if (t + 3 < NT) {
            asm volatile("s_waitcnt vmcnt(4)" ::: "memory");
        } else {
            asm volatile("s_waitcnt vmcnt(0)" ::: "memory");
        }
        __builtin_amdgcn_sched_barrier(0);
        __builtin_amdgcn_s_barrier();
        __builtin_amdgcn_sched_barrier(0);

        cur = (cur == 2) ? 0 : cur + 1;
    }

    float* Cfp = Cf ? Cf + (size_t)blockIdx.y * M * N : nullptr;
    const bool addb = (blockIdx.y == 0);

    // epilogue: C/D layout col=lane&15, row=(lane>>4)*4+r
#pragma unroll
    for (int mi = 0; mi < 4; ++mi) {
        const int rowb = m0 + wr * 64 + mi * 16 + lq * 4;
#pragma unroll
        for (int ni = 0; ni < 4; ++ni) {
            const int col = n0 + wc * 64 + ni * 16 + l16;
            const float bv = addb ? bias[col] : 0.0f;
#pragma unroll
            for (int rr = 0; rr < 4; ++rr) {
                float v2 = acc[mi][ni][rr] + bv;
                if (act == 1) v2 = 0.5f * v2 * (1.0f + erff(v2 * 0.70710678118654752f));
                const size_t idx = (size_t)(rowb + rr) * N + col;
                if (Cfp) Cfp[idx] = v2;
                if (Cb) Cb[idx] = __float2bfloat16(v2);
            }
        }
    }
}

// ---------------- flash attention ----------------
__global__ __launch_bounds__(256) void k_attn(const __hip_bfloat16* __restrict__ qkv,
                                              const int* __restrict__ seq,
                                              const float* __restrict__ dist_emb,
                                              __hip_bfloat16* __restrict__ out) {
    const int qb = blockIdx.x, h = blockIdx.y, b = blockIdx.z;
    const int q0 = qb * 64;
    const int tid = threadIdx.x, lane = tid & 63, w = tid >> 6;
    const int l16 = lane & 15, lq = lane >> 4;

    __shared__ __align__(16) __hip_bfloat16 Ks[64 * 64];
    __shared__ __align__(16) __hip_bfloat16 Vs[64 * 64];
    __shared__ __align__(16) __hip_bfloat16 Ps[4 * 16 * 64];
    __shared__ float bias_l[513];
    __shared__ float pad_l[512];

    for (int i = tid; i < 513; i += 256) bias_l[i] = dist_emb[i * 16 + h];
    for (int i = tid; i < 512; i += 256) pad_l[i] = (seq[b * 512 + i] == 0) ? -1e9f : 0.0f;

    const int qrowA = q0 + w * 16 + l16;
    const __hip_bfloat16* qptr = qkv + (size_t)(b * 512 + qrowA) * 3072 + h * 64;
    Frag8 qf[2];
    qf[0].v = *(const s16x8*)(qptr + lq * 8);
    qf[1].v = *(const s16x8*)(qptr + 32 + lq * 8);

    f32x4 oacc[4] = {};
    float mrow[4] = {-1e30f, -1e30f, -1e30f, -1e30f};
    float lrow[4] = {0.f, 0.f, 0.f, 0.f};
    char* PsW = (char*)Ps + w * 2048;

    for (int kt = 0; kt <= qb; ++kt) {
        __syncthreads();
#pragma unroll
        for (int i = 0; i < 2; ++i) {
            const int c = i * 256 + tid;
            const int kr = c >> 3, sl = c & 7;
            const size_t srow = (size_t)(b * 512 + kt * 64 + kr) * 3072 + h * 64;
            const s16x8 kv = *(const s16x8*)(qkv + srow + 1024 + sl * 8);
            *(s16x8*)((char*)Ks + kr * 128 + ((sl ^ (kr & 7)) * 16)) = kv;
            const s16x8 vv = *(const s16x8*)(qkv + srow + 2048 + sl * 8);
#pragma unroll
            for (int j = 0; j < 8; ++j) {
                const int d = sl * 8 + j;
                *(short*)((char*)Vs + d * 128 + (((kr >> 3) ^ (d & 7)) * 16) + (kr & 7) * 2) = vv[j];
            }
        }
        __syncthreads();

        f32x4 sacc[4] = {};
#pragma unroll
        for (int ks = 0; ks < 2; ++ks) {
#pragma unroll
            for (int nf = 0; nf < 4; ++nf) {
                const int key = nf * 16 + l16;
                Frag8 kf;
                kf.v = *(const s16x8*)((const char*)Ks + key * 128 + (((ks * 4 + lq) ^ (key & 7)) * 16));
                sacc[nf] = mfma16(qf[ks], kf, sacc[nf]);
            }
        }

        float pvv[4][4];
#pragma unroll
        for (int nf = 0; nf < 4; ++nf) {
            const int keyg = kt * 64 + nf * 16 + l16;
            const float padv = pad_l[keyg];
#pragma unroll
            for (int rr = 0; rr < 4; ++rr) {
                const int qg = q0 + w * 16 + lq * 4 + rr;
                pvv[nf][rr] = (keyg > qg) ? -1e9f
                            : sacc[nf][rr] * 0.125f + bias_l[qg - keyg] + padv;
            }
        }

#pragma unroll
        for (int rr = 0; rr < 4; ++rr) {
            float tm = fmaxf(fmaxf(pvv[0][rr], pvv[1][rr]), fmaxf(pvv[2][rr], pvv[3][rr]));
#pragma unroll
            for (int off = 1; off < 16; off <<= 1) tm = fmaxf(tm, __shfl_xor(tm, off, 64));
            const float mnew = fmaxf(mrow[rr], tm);
            const float sf = __expf(mrow[rr] - mnew);
            mrow[rr] = mnew;
            float ts = 0.f;
#pragma unroll
            for (int nf = 0; nf < 4; ++nf) {
                const float pe = __expf(pvv[nf][rr] - mnew);
                pvv[nf][rr] = pe;
                ts += pe;
            }
#pragma unroll
            for (int off = 1; off < 16; off <<= 1) ts += __shfl_xor(ts, off, 64);
            lrow[rr] = lrow[rr] * sf + ts;
            oacc[0][rr] *= sf; oacc[1][rr] *= sf; oacc[2][rr] *= sf; oacc[3][rr] *= sf;
        }

#pragma unroll
        for (int nf = 0; nf < 4; ++nf) {
            const int cc = nf * 16 + l16;
            const int slot = cc >> 3, rem = cc & 7;
#pragma unroll
            for (int rr = 0; rr < 4; ++rr) {
                const int row = lq * 4 + rr;
                *(short*)(PsW + row * 128 + ((slot ^ (row & 7)) * 16) + rem * 2) =
                    (short)bf16bits(pvv[nf][rr]);
            }
        }
        __syncthreads();

#pragma unroll
        for (int ks = 0; ks < 2; ++ks) {
            Frag8 pf;
            pf.v = *(const s16x8*)(PsW + l16 * 128 + (((ks * 4 + lq) ^ (l16 & 7)) * 16));
#pragma unroll
            for (int nf = 0; nf < 4; ++nf) {
                const int d = nf * 16 + l16;
                Frag8 vf;
                vf.v = *(const s16x8*)((const char*)Vs + d * 128 + (((ks * 4 + lq) ^ (d & 7)) * 16));
                oacc[nf] = mfma16(pf, vf, oacc[nf]);
            }
        }
    }

#pragma unroll
    for (int nf = 0; nf < 4; ++nf) {
        const int d = nf * 16 + l16;
#pragma unroll
        for (int rr = 0; rr < 4; ++rr) {
            const int qg = q0 + w * 16 + lq * 4 + rr;
            out[(size_t)(b * 512 + qg) * 1024 + h * 64 + d] = __float2bfloat16(oacc[nf][rr] / lrow[rr]);
        }
    }
}

// ---------------- fused residual add (up to 2 partials) + LayerNorm ----------------
__global__ __launch_bounds__(256) void k_add_ln(const float* __restrict__ x,
                                                const float* __restrict__ res0,
                                                const float* __restrict__ res1,
                                                const float* __restrict__ gamma,
                                                const float* __restrict__ beta,
                                                float* __restrict__ xout,
                                                __hip_bfloat16* __restrict__ bout) {
    const int t = blockIdx.x;
    const int tid = threadIdx.x;
    float4 y = *(const float4*)(x + (size_t)t * 1024 + tid * 4);
    if (res0) {
        const float4 rv = *(const float4*)(res0 + (size_t)t * 1024 + tid * 4);
        y.x += rv.x; y.y += rv.y; y.z += rv.z; y.w += rv.w;
    }
    if (res1) {
        const float4 rv = *(const float4*)(res1 + (size_t)t * 1024 + tid * 4);
        y.x += rv.x; y.y += rv.y; y.z += rv.z; y.w += rv.w;
    }
    float s = y.x + y.y + y.z + y.w;
    float s2 = y.x * y.x + y.y * y.y + y.z * y.z + y.w * y.w;
#pragma unroll
    for (int off = 32; off >= 1; off >>= 1) {
        s += __shfl_xor(s, off, 64);
        s2 += __shfl_xor(s2, off, 64);
    }
    __shared__ float red[8];
    const int w = tid >> 6, lane = tid & 63;
    if (lane == 0) { red[w] = s; red[4 + w] = s2; }
    __syncthreads();
    const float tot = red[0] + red[1] + red[2] + red[3];
    const float tot2 = red[4] + red[5] + red[6] + red[7];
    const float mean = tot * (1.0f / 1024.0f);
    const float var = tot2 * (1.0f / 1024.0f) - mean * mean;
    const float inv = rsqrtf(var + 1e-5f);
    const float4 g = *(const float4*)(gamma + tid * 4);
    const float4 bb = *(const float4*)(beta + tid * 4);
    float4 o;
    o.x = (y.x - mean) * inv * g.x + bb.x;
    o.y = (y.y - mean) * inv * g.y + bb.y;
    o.z = (y.z - mean) * inv * g.z + bb.z;
    o.w = (y.w - mean) * inv * g.w + bb.w;
    *(float4*)(xout + (size_t)t * 1024 + tid * 4) = o;
    ushort4 u;
    u.x = bf16bits(o.x); u.y = bf16bits(o.y); u.z = bf16bits(o.z); u.w = bf16bits(o.w);
    *(ushort4*)((unsigned short*)bout + (size_t)t * 1024 + tid * 4) = u;
}

// ---------------- host ----------------
extern "C" void kernel_launch(void* const* d_in, const int* in_sizes, int n_in,
                              void* d_out, int out_size, void* d_ws, size_t ws_size,
                              hipStream_t stream) {
    const int* seq = (const int*)d_in[0];
    const float* tok = (const float*)d_in[1];
    const float* dist = (const float*)d_in[2];
    const float* Wqkv = (const float*)d_in[3];
    const float* bqkv = (const float*)d_in[4];
    const float* Wo = (const float*)d_in[5];
    const float* bo = (const float*)d_in[6];
    const float* W1 = (const float*)d_in[7];
    const float* b1 = (const float*)d_in[8];
    const float* W2 = (const float*)d_in[9];
    const float* b2 = (const float*)d_in[10];
    const float* ln1s = (const float*)d_in[11];
    const float* ln1b = (const float*)d_in[12];
    const float* ln2s = (const float*)d_in[13];
    const float* ln2b = (const float*)d_in[14];
    const float* lnfs = (const float*)d_in[15];
    const float* lnfb = (const float*)d_in[16];
    const float* Wg = (const float*)d_in[17];
    const float* bg = (const float*)d_in[18];
    float* out = (float*)d_out;

    char* p = (char*)d_ws;
    auto take = [&](size_t bytes) {
        char* r = p;
        p += (bytes + 255) & ~(size_t)255;
        return r;
    };
    __hip_bfloat16* wqkv_b = (__hip_bfloat16*)take((size_t)6 * 3072 * 1024 * 2);
    __hip_bfloat16* wo_b = (__hip_bfloat16*)take((size_t)6 * 1024 * 1024 * 2);
    __hip_bfloat16* w1_b = (__hip_bfloat16*)take((size_t)6 * 4096 * 1024 * 2);
    __hip_bfloat16* w2_b = (__hip_bfloat16*)take((size_t)6 * 1024 * 4096 * 2);
    __hip_bfloat16* wg_b = (__hip_bfloat16*)take((size_t)32000 * 1024 * 2);
    float* xf = (float*)take((size_t)2048 * 1024 * 4);
    __hip_bfloat16* xb = (__hip_bfloat16*)take((size_t)2048 * 1024 * 2);
    __hip_bfloat16* qkvb = (__hip_bfloat16*)take((size_t)2048 * 3072 * 2);
    __hip_bfloat16* hb = (__hip_bfloat16*)take((size_t)2048 * 4096 * 2);
    __hip_bfloat16* ab = (__hip_bfloat16*)take((size_t)2048 * 1024 * 2);
    float* tmpf = (float*)take((size_t)2 * 2048 * 1024 * 4);
    float* tmpf1 = tmpf + (size_t)2048 * 1024;

    auto conv = [&](const float* src, __hip_bfloat16* dst, long n) {
        k_f32_to_bf16<<<dim3((unsigned)(n / 1024)), dim3(256), 0, stream>>>(src, dst, n);
    };
    conv(Wqkv, wqkv_b, (long)6 * 3072 * 1024);
    conv(Wo, wo_b, (long)6 * 1024 * 1024);
    conv(W1, w1_b, (long)6 * 4096 * 1024);
    conv(W2, w2_b, (long)6 * 1024 * 4096);
    conv(Wg, wg_b, (long)32000 * 1024);

    k_embed<<<dim3(2048), dim3(256), 0, stream>>>(seq, tok, xf, xb);

    for (int l = 0; l < 6; ++l) {
        // QKV: 2048 x 3072 x 1024, bf16 out
        k_gemm<0><<<dim3(16 * 24), dim3(256), 0, stream>>>(
            xb, wqkv_b + (size_t)l * 3072 * 1024, bqkv + l * 3072, nullptr, qkvb,
            2048, 3072, 1024, 1024, 16, 0);
        k_attn<<<dim3(8, 16, 4), dim3(256), 0, stream>>>(qkvb, seq, dist, ab);
        // Wo: 2048 x 1024 x 1024, split-K=2 -> f32 partials
        k_gemm<1><<<dim3(16 * 8, 2), dim3(256), 0, stream>>>(
            ab, wo_b + (size_t)l * 1024 * 1024, bo + l * 1024, tmpf, nullptr,
            2048, 1024, 1024, 512, 16, 0);
        k_add_ln<<<dim3(2048), dim3(256), 0, stream>>>(xf, tmpf, tmpf1, ln1s + l * 1024,
                                                       ln1b + l * 1024, xf, xb);
        // FFN1: 2048 x 4096 x 1024, GELU, bf16 out
        k_gemm<2><<<dim3(16 * 32), dim3(256), 0, stream>>>(
            xb, w1_b + (size_t)l * 4096 * 1024, b1 + l * 4096, nullptr, hb,
            2048, 4096, 1024, 1024, 16, 1);
        // FFN2: 2048 x 1024 x 4096, split-K=2 -> f32 partials
        k_gemm<3><<<dim3(16 * 8, 2), dim3(256), 0, stream>>>(
            hb, w2_b + (size_t)l * 1024 * 4096, b2 + l * 1024, tmpf, nullptr,
            2048, 1024, 4096, 2048, 16, 0);
        k_add_ln<<<dim3(2048), dim3(256), 0, stream>>>(xf, tmpf, tmpf1, ln2s + l * 1024,
                                                       ln2b + l * 1024, xf, xb);
    }
    k_add_ln<<<dim3(2048), dim3(256), 0, stream>>>(xf, nullptr, nullptr, lnfs, lnfb, xf, xb);
    // vocab: 2048 x 32000 x 1024, f32 out
    k_gemm<4><<<dim3(16 * 250), dim3(256), 0, stream>>>(xb, wg_b, bg, out, nullptr,
                                                        2048, 32000, 1024, 1024, 16, 0);
}